// Round 2
// baseline (16774.429 us; speedup 1.0000x reference)
//
#include <hip/hip_runtime.h>
#include <hip/hip_bf16.h>

#define BB 256
#define TT 512
#define HH 512

#define WSTRIDE 516   // padded LDS row stride for W_hh slice (floats)
#define HSTRIDE 260   // padded LDS row stride for h chunk (floats)

// ---------------- mask encoding detection ----------------
// s_onehot is a bool [B,T,2] array of 0/1 values. Element storage may be u8,
// i32, f32, or i64 depending on harness marshaling; detect from byte pattern.
__global__ void detect_k(const unsigned char* __restrict__ s, int* __restrict__ flags)
{
    int a = 0, b = 0, c = 0;
    for (int i = threadIdx.x; i < BB * TT * 2; i += blockDim.x) {
        unsigned char v = s[i];
        if (v) {
            int m = i & 3;
            if (m == 1) a = 1;
            else if (m >= 2) b = 1;
            if ((i & 7) == 4) c = 1;
        }
    }
    if (a) atomicOr(flags, 1);
    if (b) atomicOr(flags, 2);
    if (c) atomicOr(flags, 4);
}

// canon[bt] = bit0: band g valid, bit1: band r valid.  valid == (bit0|bit1).
__global__ void canon_k(const void* __restrict__ s, const int* __restrict__ flags,
                        unsigned char* __restrict__ canon)
{
    int bt = blockIdx.x * blockDim.x + threadIdx.x;
    if (bt >= BB * TT) return;
    int f = *flags;
    int sg, sr;
    if (f & 1) {
        const unsigned char* p = (const unsigned char*)s;
        sg = p[2 * bt] != 0; sr = p[2 * bt + 1] != 0;
    } else if (f & 2) {
        const float* p = (const float*)s;
        sg = p[2 * bt] != 0.0f; sr = p[2 * bt + 1] != 0.0f;
    } else if (f & 4) {
        const int* p = (const int*)s;
        sg = p[2 * bt] != 0; sr = p[2 * bt + 1] != 0;
    } else {
        const long long* p = (const long long*)s;
        sg = p[2 * bt] != 0; sr = p[2 * bt + 1] != 0;
    }
    canon[bt] = (unsigned char)(sg | (sr << 1));
}

// ---------------- W1 transpose (for coalesced FF reads) ----------------
__global__ void w1t_k(const float* __restrict__ W1, float* __restrict__ W1T)
{
    int idx = blockIdx.x * blockDim.x + threadIdx.x;
    if (idx >= HH * HH) return;
    int j = idx / HH;
    int k = idx % HH;
    W1T[k * HH + j] = W1[idx];
}

// ---------------- persistent GRU ----------------
// 256 WGs x 256 threads, 1 WG/CU (132KB LDS + launch_bounds -> co-resident).
// 8 groups of 32 WGs (group = blockIdx&7, XCD-local under %8 mapping).
// Group g owns batches [32g, 32g+32); WG wi=blockIdx>>3 owns h-cols
// [16wi,16wi+16) i.e. W_hh gate-row triples, held stationary in LDS (fp32).
// Per step: stage group h (2 chunks of 256 k) into LDS, each thread computes
// 2 batches x 1 col x 3 gates, pointwise GRU update, write h + decz(bf16),
// then a monotonic-counter agent-scope barrier across the 32 WGs.
__global__ __launch_bounds__(256, 1) void gru_persist(
    const float* __restrict__ dtime, const unsigned char* __restrict__ canon,
    const float* __restrict__ Wih, const float* __restrict__ Whh,
    const float* __restrict__ bih, const float* __restrict__ bhh,
    float* __restrict__ gbuf,            // [2][BB][HH]
    __hip_bfloat16* __restrict__ decz,   // [BB][TT][HH]
    int* __restrict__ ctr)               // 8 counters, stride 32 ints
{
    __shared__ float wlds[48 * WSTRIDE]; // 99,072 B
    __shared__ float hl[32 * HSTRIDE];   // 33,280 B

    const int w  = blockIdx.x;
    const int g  = w & 7;
    const int wi = w >> 3;
    const int c0 = wi * 16;
    const int tid = threadIdx.x;
    const int c  = tid & 15;     // col within tile
    const int b2 = tid >> 4;     // 0..15 batch slot (handles b2 and b2+16)

    // ---- load stationary W_hh slice: LDS row = gate*16 + i ----
    for (int idx = tid; idx < 48 * 128; idx += 256) {
        int row = idx >> 7, k4 = idx & 127;
        int gate = row >> 4, i = row & 15;
        float4 v = *(const float4*)(Whh + ((size_t)gate * HH + c0 + i) * HH + k4 * 4);
        *(float4*)(wlds + row * WSTRIDE + k4 * 4) = v;
    }

    // ---- per-thread input-projection constants for col j ----
    const int j = c0 + c;
    const int r1 = HH + j, r2 = 2 * HH + j;
    const float wi00 = Wih[j * 3],  wi01 = Wih[j * 3 + 1],  wi02 = Wih[j * 3 + 2];
    const float wi10 = Wih[r1 * 3], wi11 = Wih[r1 * 3 + 1], wi12 = Wih[r1 * 3 + 2];
    const float wi20 = Wih[r2 * 3], wi21 = Wih[r2 * 3 + 1], wi22 = Wih[r2 * 3 + 2];
    const float bi0 = bih[j], bi1 = bih[r1], bi2 = bih[r2];
    const float bh0 = bhh[j], bh1 = bhh[r1], bh2 = bhh[r2];

    const int bA = g * 32 + b2;
    const int bB = bA + 16;
    int* gctr = ctr + g * 32;

    __syncthreads();

    int tgt = 32;
    for (int t = 0; t < TT; ++t) {
        const float* hin = gbuf + (size_t)(t & 1) * BB * HH;
        float*       hout = gbuf + (size_t)((t + 1) & 1) * BB * HH;

        float a0A = 0.f, a1A = 0.f, a2A = 0.f;
        float a0B = 0.f, a1B = 0.f, a2B = 0.f;

        for (int ch = 0; ch < 2; ++ch) {
            // stage h chunk: 32 rows x 256 k
            for (int idx = tid; idx < 32 * 64; idx += 256) {
                int row = idx >> 6, k4 = idx & 63;
                float4 v = *(const float4*)(hin + (size_t)(g * 32 + row) * HH + ch * 256 + k4 * 4);
                *(float4*)(hl + row * HSTRIDE + k4 * 4) = v;
            }
            __syncthreads();

            const float4* hA4 = (const float4*)(hl + b2 * HSTRIDE);
            const float4* hB4 = (const float4*)(hl + (b2 + 16) * HSTRIDE);
            const float4* w04 = (const float4*)(wlds + (0 * 16 + c) * WSTRIDE) + ch * 64;
            const float4* w14 = (const float4*)(wlds + (1 * 16 + c) * WSTRIDE) + ch * 64;
            const float4* w24 = (const float4*)(wlds + (2 * 16 + c) * WSTRIDE) + ch * 64;

#pragma unroll 4
            for (int k4 = 0; k4 < 64; ++k4) {
                float4 ha = hA4[k4], hb = hB4[k4];
                float4 x0 = w04[k4], x1 = w14[k4], x2 = w24[k4];
                a0A += ha.x * x0.x + ha.y * x0.y + ha.z * x0.z + ha.w * x0.w;
                a1A += ha.x * x1.x + ha.y * x1.y + ha.z * x1.z + ha.w * x1.w;
                a2A += ha.x * x2.x + ha.y * x2.y + ha.z * x2.z + ha.w * x2.w;
                a0B += hb.x * x0.x + hb.y * x0.y + hb.z * x0.z + hb.w * x0.w;
                a1B += hb.x * x1.x + hb.y * x1.y + hb.z * x1.z + hb.w * x1.w;
                a2B += hb.x * x2.x + hb.y * x2.y + hb.z * x2.z + hb.w * x2.w;
            }
            __syncthreads();
        }

        // ---- pointwise GRU update, batch A ----
        {
            float dt = dtime[bA * TT + t];
            unsigned char cn = canon[bA * TT + t];
            float sg = (cn & 1) ? 1.f : 0.f, sr = (cn & 2) ? 1.f : 0.f;
            float xr = wi00 * dt + wi01 * sg + wi02 * sr + bi0;
            float xz = wi10 * dt + wi11 * sg + wi12 * sr + bi1;
            float xn = wi20 * dt + wi21 * sg + wi22 * sr + bi2;
            float rr = 1.f / (1.f + __expf(-(xr + a0A + bh0)));
            float zz = 1.f / (1.f + __expf(-(xz + a1A + bh1)));
            float nn = tanhf(xn + rr * (a2A + bh2));
            float hp = hin[(size_t)bA * HH + j];
            float hnew = (1.f - zz) * nn + zz * hp;
            float ho = cn ? hnew : hp;
            hout[(size_t)bA * HH + j] = ho;
            decz[((size_t)bA * TT + t) * HH + j] = __float2bfloat16(ho);
        }
        // ---- pointwise GRU update, batch B ----
        {
            float dt = dtime[bB * TT + t];
            unsigned char cn = canon[bB * TT + t];
            float sg = (cn & 1) ? 1.f : 0.f, sr = (cn & 2) ? 1.f : 0.f;
            float xr = wi00 * dt + wi01 * sg + wi02 * sr + bi0;
            float xz = wi10 * dt + wi11 * sg + wi12 * sr + bi1;
            float xn = wi20 * dt + wi21 * sg + wi22 * sr + bi2;
            float rr = 1.f / (1.f + __expf(-(xr + a0B + bh0)));
            float zz = 1.f / (1.f + __expf(-(xz + a1B + bh1)));
            float nn = tanhf(xn + rr * (a2B + bh2));
            float hp = hin[(size_t)bB * HH + j];
            float hnew = (1.f - zz) * nn + zz * hp;
            float ho = cn ? hnew : hp;
            hout[(size_t)bB * HH + j] = ho;
            decz[((size_t)bB * TT + t) * HH + j] = __float2bfloat16(ho);
        }

        // ---- group barrier (monotonic counter, agent scope) ----
        __syncthreads();   // drains this WG's global writes (vmcnt(0) before s_barrier)
        if (tid == 0) {
            __hip_atomic_fetch_add(gctr, 1, __ATOMIC_RELEASE, __HIP_MEMORY_SCOPE_AGENT);
            while (__hip_atomic_load(gctr, __ATOMIC_ACQUIRE, __HIP_MEMORY_SCOPE_AGENT) < tgt)
                __builtin_amdgcn_s_sleep(2);
        }
        __syncthreads();
        tgt += 32;
    }
}

// ---------------- FF head: decx = W2 . relu(W1 . decz + b1) + b2 ----------------
__global__ __launch_bounds__(512) void ff_k(
    const __hip_bfloat16* __restrict__ decz, const float* __restrict__ W1T,
    const float* __restrict__ b1, const float* __restrict__ W2,
    const float* __restrict__ b2, float* __restrict__ decx)
{
    __shared__ float xl[16 * 512];
    __shared__ float red[8];

    const int row0 = blockIdx.x * 16;
    for (int idx = threadIdx.x; idx < 16 * 512; idx += 512) {
        int rr = idx >> 9, k = idx & 511;
        xl[rr * 512 + k] = __bfloat162float(decz[(size_t)(row0 + rr) * HH + k]);
    }
    __syncthreads();

    const int j = threadIdx.x;
    float acc[16];
#pragma unroll
    for (int rr = 0; rr < 16; rr++) acc[rr] = 0.f;

    for (int k = 0; k < 512; k++) {
        float wv = W1T[k * 512 + j];
#pragma unroll
        for (int rr = 0; rr < 16; rr++) acc[rr] += xl[rr * 512 + k] * wv;
    }

    const float w2j = W2[j];
    const float b1j = b1[j];
    for (int rr = 0; rr < 16; rr++) {
        float v = w2j * fmaxf(acc[rr] + b1j, 0.f);
#pragma unroll
        for (int o = 32; o > 0; o >>= 1) v += __shfl_down(v, o, 64);
        if ((threadIdx.x & 63) == 0) red[threadIdx.x >> 6] = v;
        __syncthreads();
        if (threadIdx.x == 0) {
            float s = 0.f;
#pragma unroll
            for (int w = 0; w < 8; w++) s += red[w];
            decx[row0 + rr] = s + b2[0];
        }
        __syncthreads();
    }
}

// ---------------- serial -> parallel scatter ----------------
__global__ void scatter_k(const unsigned char* __restrict__ canon,
                          const float* __restrict__ decx, float* __restrict__ out)
{
    int id = blockIdx.x * blockDim.x + threadIdx.x;
    if (id >= 2 * BB) return;
    int kb = id >> 8, b = id & 255;
    int cnt = 0;
    for (int t = 0; t < TT; t++) {
        unsigned char c = canon[b * TT + t];
        if ((c >> kb) & 1) {
            out[((size_t)kb * BB + b) * TT + cnt] = decx[b * TT + t];
            cnt++;
        }
    }
}

extern "C" void kernel_launch(void* const* d_in, const int* in_sizes, int n_in,
                              void* d_out, int out_size, void* d_ws, size_t ws_size,
                              hipStream_t stream)
{
    const float* dtime    = (const float*)d_in[0];
    const void*  s_onehot = d_in[1];
    // d_in[2] (onehot/valid) is never read: valid == s_g | s_r by construction.
    const float* encz = (const float*)d_in[3];
    const float* Wih  = (const float*)d_in[4];
    const float* Whh  = (const float*)d_in[5];
    const float* bih  = (const float*)d_in[6];
    const float* bhh  = (const float*)d_in[7];
    const float* W1   = (const float*)d_in[8];
    const float* b1   = (const float*)d_in[9];
    const float* W2   = (const float*)d_in[10];
    const float* b2   = (const float*)d_in[11];

    char* ws = (char*)d_ws;
    int*            ctr   = (int*)ws;                              // 1024 B
    unsigned char*  canon = (unsigned char*)(ws + 1024);           // 131072 B
    int*            flags = (int*)(ws + 1024 + BB * TT);           // reuse tail pad of canon region
    float*          gbuf  = (float*)(ws + 1024 + BB * TT + 256);   // 2*BB*HH*4
    float*          decx  = gbuf + 2 * BB * HH;                    // BB*TT*4
    float*          W1T   = decx + BB * TT;                        // HH*HH*4
    __hip_bfloat16* decz  = (__hip_bfloat16*)(W1T + HH * HH);      // BB*TT*HH*2

    hipMemsetAsync(ws, 0, 1024 + BB * TT + 256, stream);  // ctr + canon + flags
    detect_k<<<1, 256, 0, stream>>>((const unsigned char*)s_onehot, flags);
    canon_k<<<(BB * TT + 255) / 256, 256, 0, stream>>>(s_onehot, flags, canon);
    hipMemcpyAsync(gbuf, encz, (size_t)BB * HH * sizeof(float),
                   hipMemcpyDeviceToDevice, stream);
    w1t_k<<<(HH * HH + 255) / 256, 256, 0, stream>>>(W1, W1T);

    gru_persist<<<256, 256, 0, stream>>>(dtime, canon, Wih, Whh, bih, bhh,
                                         gbuf, decz, ctr);

    ff_k<<<BB * TT / 16, 512, 0, stream>>>(decz, W1T, b1, W2, b2, decx);

    hipMemsetAsync(d_out, 0, (size_t)out_size * sizeof(float), stream);
    scatter_k<<<2, 256, 0, stream>>>(canon, decx, (float*)d_out);
}

// Round 3
// 7880.965 us; speedup vs baseline: 2.1285x; 2.1285x over previous
//
#include <hip/hip_runtime.h>
#include <hip/hip_bf16.h>

#define BB 256
#define TT 512
#define HH 512

typedef float floatx4 __attribute__((ext_vector_type(4)));
typedef short short8 __attribute__((ext_vector_type(8)));

__device__ __forceinline__ unsigned short f2bf(float f) {
    union { float f; unsigned u; } v; v.f = f;
    unsigned r = v.u + 0x7fffu + ((v.u >> 16) & 1u);
    return (unsigned short)(r >> 16);
}
__device__ __forceinline__ float bf2f(unsigned short h) {
    union { unsigned u; float f; } v; v.u = ((unsigned)h) << 16;
    return v.f;
}

// ---------------- mask encoding detection ----------------
__global__ void detect_k(const unsigned char* __restrict__ s, int* __restrict__ flags)
{
    int a = 0, b = 0, c = 0;
    for (int i = blockIdx.x * blockDim.x + threadIdx.x; i < BB * TT * 2;
         i += gridDim.x * blockDim.x) {
        unsigned char v = s[i];
        if (v) {
            int m = i & 3;
            if (m == 1) a = 1;
            else if (m >= 2) b = 1;
            if ((i & 7) == 4) c = 1;
        }
    }
    if (a) atomicOr(flags, 1);
    if (b) atomicOr(flags, 2);
    if (c) atomicOr(flags, 4);
}

__global__ void canon_k(const void* __restrict__ s, const int* __restrict__ flags,
                        unsigned char* __restrict__ canon)
{
    int bt = blockIdx.x * blockDim.x + threadIdx.x;
    if (bt >= BB * TT) return;
    int f = *flags;
    int sg, sr;
    if (f & 1) {
        const unsigned char* p = (const unsigned char*)s;
        sg = p[2 * bt] != 0; sr = p[2 * bt + 1] != 0;
    } else if (f & 2) {
        const float* p = (const float*)s;
        sg = p[2 * bt] != 0.0f; sr = p[2 * bt + 1] != 0.0f;
    } else if (f & 4) {
        const int* p = (const int*)s;
        sg = p[2 * bt] != 0; sr = p[2 * bt + 1] != 0;
    } else {
        const long long* p = (const long long*)s;
        sg = p[2 * bt] != 0; sr = p[2 * bt + 1] != 0;
    }
    canon[bt] = (unsigned char)(sg | (sr << 1));
}

// ---------------- h0 = encz split into bf16 hi/lo ----------------
__global__ void h0_k(const float* __restrict__ encz,
                     unsigned short* __restrict__ Hh, unsigned short* __restrict__ Hl)
{
    int i = blockIdx.x * blockDim.x + threadIdx.x;
    if (i >= BB * HH) return;
    float f = encz[i];
    unsigned short hi = f2bf(f);
    Hh[i] = hi;
    Hl[i] = f2bf(f - bf2f(hi));
}

// ---------------- W1 transpose (runs AFTER gru; aliases Hh/Hl region) ----------------
__global__ void w1t_k(const float* __restrict__ W1, float* __restrict__ W1T)
{
    int idx = blockIdx.x * blockDim.x + threadIdx.x;
    if (idx >= HH * HH) return;
    int j = idx / HH;
    int k = idx % HH;
    W1T[k * HH + j] = W1[idx];
}

// ---------------- persistent MFMA GRU ----------------
// 256 WGs x 384 threads (6 waves). group g = blockIdx&15 (XCD-pure), wi = blockIdx>>4.
// Group owns batches [16g,16g+16) (M = one 16x16 MFMA tile). WG owns cols [32wi,32wi+32).
// Wave w = (gate = w>>1, colhalf = w&1): one 16-col N-tile; W_hh fragments (bf16 hi+lo)
// stationary in 128 VGPRs. h staged to LDS in exact A-fragment layout (conflict-free
// ds_read_b128). Split-bf16: acc = Ah*Bh + Ah*Bl + Al*Bh (3 independent MFMA chains).
__global__ __launch_bounds__(384, 2) void gru_mfma(
    const float* __restrict__ dtime, const unsigned char* __restrict__ canon,
    const float* __restrict__ Wih, const float* __restrict__ Whh,
    const float* __restrict__ bih, const float* __restrict__ bhh,
    unsigned short* __restrict__ Hh, unsigned short* __restrict__ Hl, // [2][BB][HH]
    unsigned short* __restrict__ decz,                                // [BB][TT][HH] bf16 bits
    int* __restrict__ ctr)
{
    __shared__ unsigned short hfh[16 * 512]; // A-frags hi: [kt][lane][8]  16KB
    __shared__ unsigned short hfl[16 * 512]; // A-frags lo                 16KB
    __shared__ float dtl[16 * 512];          // group dtime                32KB
    __shared__ unsigned char cnl[16 * 512];  // group canon                 8KB
    __shared__ float exch[6 * 256];          // C-frag exchange             6KB

    const int g   = blockIdx.x & 15;
    const int wi  = blockIdx.x >> 4;
    const int tid = threadIdx.x;
    const int w   = tid >> 6, l = tid & 63;
    const int bg0 = g * 16;

    // preload dtime/canon for the group (contiguous copies)
    for (int it = tid; it < 2048; it += 384)
        *(float4*)(dtl + it * 4) = *(const float4*)(dtime + (size_t)bg0 * TT + it * 4);
    for (int it = tid; it < 2048; it += 384)
        *(unsigned int*)(cnl + it * 4) = *(const unsigned int*)(canon + (size_t)bg0 * TT + it * 4);

    // ---- stationary B fragments (W_hh rows for this wave's N-tile) ----
    const int gate = w >> 1, ch = w & 1;
    const int rB   = gate * HH + wi * 32 + ch * 16 + (l & 15);
    const int kq4  = ((l >> 4) & 3) * 4;
    short8 Bh[16], Bl[16];
#pragma unroll
    for (int kt = 0; kt < 16; ++kt) {
        const float* wp = Whh + (size_t)rB * HH + kt * 32 + kq4;
        float4 f0 = *(const float4*)(wp);
        float4 f1 = *(const float4*)(wp + 16);
        float fs[8] = {f0.x, f0.y, f0.z, f0.w, f1.x, f1.y, f1.z, f1.w};
        short8 bh, bl;
#pragma unroll
        for (int j = 0; j < 8; ++j) {
            unsigned short hb = f2bf(fs[j]);
            bh[j] = (short)hb;
            bl[j] = (short)f2bf(fs[j] - bf2f(hb));
        }
        Bh[kt] = bh; Bl[kt] = bl;
    }

    // ---- pointwise per-thread constants (threads < 256 handle 2 (b,col) pairs) ----
    float pw[2][15];
    int pb[2], pj[2];
    if (tid < 256) {
#pragma unroll
        for (int p = 0; p < 2; ++p) {
            int idx = tid * 2 + p;
            int jl = idx & 31, b = idx >> 5;
            int j = wi * 32 + jl;
            int r1 = HH + j, r2 = 2 * HH + j;
            pb[p] = b; pj[p] = jl;
            pw[p][0] = Wih[j * 3];  pw[p][1] = Wih[j * 3 + 1];  pw[p][2] = Wih[j * 3 + 2];
            pw[p][3] = Wih[r1 * 3]; pw[p][4] = Wih[r1 * 3 + 1]; pw[p][5] = Wih[r1 * 3 + 2];
            pw[p][6] = Wih[r2 * 3]; pw[p][7] = Wih[r2 * 3 + 1]; pw[p][8] = Wih[r2 * 3 + 2];
            pw[p][9] = bih[j]; pw[p][10] = bih[r1]; pw[p][11] = bih[r2];
            pw[p][12] = bhh[j]; pw[p][13] = bhh[r1]; pw[p][14] = bhh[r2];
        }
    }

    int* gc = ctr + g * 32;
    __syncthreads();

    for (int t = 0; t < TT; ++t) {
        const unsigned short* Hhc = Hh + (size_t)(t & 1) * BB * HH;
        const unsigned short* Hlc = Hl + (size_t)(t & 1) * BB * HH;
        unsigned short* Hhn = Hh + (size_t)((t + 1) & 1) * BB * HH;
        unsigned short* Hln = Hl + (size_t)((t + 1) & 1) * BB * HH;

        // ---- stage h(t) into A-fragment layout ----
        for (int it = tid; it < 1024; it += 384) {
            int b = it >> 6, k0 = (it & 63) * 8;
            int kt = k0 >> 5, kin = k0 & 31;
            int kq = (kin >> 2) & 3, kh4 = (kin >> 4) * 4;
            ulonglong2 qh = *(const ulonglong2*)(Hhc + (size_t)(bg0 + b) * HH + k0);
            ulonglong2 ql = *(const ulonglong2*)(Hlc + (size_t)(bg0 + b) * HH + k0);
            int o1 = kt * 512 + (b + 16 * kq) * 8 + kh4;
            int o2 = kt * 512 + (b + 16 * (kq + 1)) * 8 + kh4;
            *(unsigned long long*)(hfh + o1) = qh.x;
            *(unsigned long long*)(hfh + o2) = qh.y;
            *(unsigned long long*)(hfl + o1) = ql.x;
            *(unsigned long long*)(hfl + o2) = ql.y;
        }
        __syncthreads();

        // ---- MFMA: 3 independent split-bf16 chains ----
        floatx4 ac0 = {0.f, 0.f, 0.f, 0.f};
        floatx4 ac1 = {0.f, 0.f, 0.f, 0.f};
        floatx4 ac2 = {0.f, 0.f, 0.f, 0.f};
#pragma unroll
        for (int kt = 0; kt < 16; ++kt) {
            short8 ah = *(const short8*)(hfh + kt * 512 + l * 8);
            short8 al = *(const short8*)(hfl + kt * 512 + l * 8);
            ac0 = __builtin_amdgcn_mfma_f32_16x16x32_bf16(ah, Bh[kt], ac0, 0, 0, 0);
            ac1 = __builtin_amdgcn_mfma_f32_16x16x32_bf16(ah, Bl[kt], ac1, 0, 0, 0);
            ac2 = __builtin_amdgcn_mfma_f32_16x16x32_bf16(al, Bh[kt], ac2, 0, 0, 0);
        }
        floatx4 acc = ac0 + ac1 + ac2;
        __syncthreads();

        *(floatx4*)(exch + w * 256 + l * 4) = acc;
        __syncthreads();

        // ---- pointwise GRU update ----
        if (tid < 256) {
#pragma unroll
            for (int p = 0; p < 2; ++p) {
                int b = pb[p], jl = pj[p];
                int lane16 = (jl & 15) + 16 * (b >> 2);
                int roff = b & 3;
                float a0 = exch[((jl >> 4)) * 256 + lane16 * 4 + roff];
                float a1 = exch[(2 + (jl >> 4)) * 256 + lane16 * 4 + roff];
                float a2 = exch[(4 + (jl >> 4)) * 256 + lane16 * 4 + roff];

                int j = wi * 32 + jl;
                int kin = j & 31, kt2 = j >> 5;
                int offA = kt2 * 512 + (b + 16 * ((kin >> 2) & 3)) * 8 + (kin >> 4) * 4 + (kin & 3);
                float hp = bf2f(hfh[offA]) + bf2f(hfl[offA]);

                float dt = dtl[b * TT + t];
                unsigned char cn = cnl[b * TT + t];
                float sg = (cn & 1) ? 1.f : 0.f, sr = (cn & 2) ? 1.f : 0.f;
                float xr = pw[p][0] * dt + pw[p][1] * sg + pw[p][2] * sr + pw[p][9];
                float xz = pw[p][3] * dt + pw[p][4] * sg + pw[p][5] * sr + pw[p][10];
                float xn = pw[p][6] * dt + pw[p][7] * sg + pw[p][8] * sr + pw[p][11];
                float rr = 1.f / (1.f + __expf(-(xr + a0 + pw[p][12])));
                float zz = 1.f / (1.f + __expf(-(xz + a1 + pw[p][13])));
                float nn = tanhf(xn + rr * (a2 + pw[p][14]));
                float hnew = (1.f - zz) * nn + zz * hp;
                float ho = cn ? hnew : hp;

                unsigned short hib = f2bf(ho);
                unsigned short lob = f2bf(ho - bf2f(hib));
                int bg = bg0 + b;
                Hhn[(size_t)bg * HH + j] = hib;
                Hln[(size_t)bg * HH + j] = lob;
                decz[((size_t)bg * TT + t) * HH + j] = hib;
            }
        }

        // ---- group barrier (monotonic counter; relaxed poll + single acquire) ----
        if (t != TT - 1) {
            __syncthreads();   // drains vmcnt before barrier -> h writes in L2
            if (tid == 0) {
                __hip_atomic_fetch_add(gc, 1, __ATOMIC_RELEASE, __HIP_MEMORY_SCOPE_AGENT);
                int tgt = (t + 1) * 16;
                while (__hip_atomic_load(gc, __ATOMIC_RELAXED, __HIP_MEMORY_SCOPE_AGENT) < tgt)
                    __builtin_amdgcn_s_sleep(1);
                (void)__hip_atomic_load(gc, __ATOMIC_ACQUIRE, __HIP_MEMORY_SCOPE_AGENT);
            }
            __syncthreads();
        }
    }
}

// ---------------- FF head ----------------
__global__ __launch_bounds__(512) void ff_k(
    const __hip_bfloat16* __restrict__ decz, const float* __restrict__ W1T,
    const float* __restrict__ b1, const float* __restrict__ W2,
    const float* __restrict__ b2, float* __restrict__ decx)
{
    __shared__ float xl[16 * 512];
    __shared__ float red[8];

    const int row0 = blockIdx.x * 16;
    for (int idx = threadIdx.x; idx < 16 * 512; idx += 512) {
        int rr = idx >> 9, k = idx & 511;
        xl[rr * 512 + k] = __bfloat162float(decz[(size_t)(row0 + rr) * HH + k]);
    }
    __syncthreads();

    const int j = threadIdx.x;
    float acc[16];
#pragma unroll
    for (int rr = 0; rr < 16; rr++) acc[rr] = 0.f;

    for (int k = 0; k < 512; k++) {
        float wv = W1T[k * 512 + j];
#pragma unroll
        for (int rr = 0; rr < 16; rr++) acc[rr] += xl[rr * 512 + k] * wv;
    }

    const float w2j = W2[j];
    const float b1j = b1[j];
    for (int rr = 0; rr < 16; rr++) {
        float v = w2j * fmaxf(acc[rr] + b1j, 0.f);
#pragma unroll
        for (int o = 32; o > 0; o >>= 1) v += __shfl_down(v, o, 64);
        if ((threadIdx.x & 63) == 0) red[threadIdx.x >> 6] = v;
        __syncthreads();
        if (threadIdx.x == 0) {
            float s = 0.f;
#pragma unroll
            for (int ww = 0; ww < 8; ww++) s += red[ww];
            decx[row0 + rr] = s + b2[0];
        }
        __syncthreads();
    }
}

// ---------------- serial -> parallel scatter ----------------
__global__ void scatter_k(const unsigned char* __restrict__ canon,
                          const float* __restrict__ decx, float* __restrict__ out)
{
    int id = blockIdx.x * blockDim.x + threadIdx.x;
    if (id >= 2 * BB) return;
    int kb = id >> 8, b = id & 255;
    int cnt = 0;
    for (int t = 0; t < TT; t++) {
        unsigned char c = canon[b * TT + t];
        if ((c >> kb) & 1) {
            out[((size_t)kb * BB + b) * TT + cnt] = decx[b * TT + t];
            cnt++;
        }
    }
}

extern "C" void kernel_launch(void* const* d_in, const int* in_sizes, int n_in,
                              void* d_out, int out_size, void* d_ws, size_t ws_size,
                              hipStream_t stream)
{
    const float* dtime    = (const float*)d_in[0];
    const void*  s_onehot = d_in[1];
    // d_in[2] (onehot/valid) never read: valid == s_g | s_r by construction.
    const float* encz = (const float*)d_in[3];
    const float* Wih  = (const float*)d_in[4];
    const float* Whh  = (const float*)d_in[5];
    const float* bih  = (const float*)d_in[6];
    const float* bhh  = (const float*)d_in[7];
    const float* W1   = (const float*)d_in[8];
    const float* b1   = (const float*)d_in[9];
    const float* W2   = (const float*)d_in[10];
    const float* b2   = (const float*)d_in[11];

    char* ws = (char*)d_ws;
    int*            ctr   = (int*)ws;                       // 2KB (16 groups x 128B)
    int*            flags = (int*)(ws + 2048);
    unsigned char*  canon = (unsigned char*)(ws + 4096);    // 128KB
    unsigned short* Hh    = (unsigned short*)(ws + 4096 + BB * TT);  // 2*BB*HH us (512KB)
    unsigned short* Hl    = Hh + 2 * BB * HH;                         // 512KB
    unsigned short* decz  = Hl + 2 * BB * HH;                         // BB*TT*HH us (128MB)
    float*          decx  = (float*)(decz + (size_t)BB * TT * HH);    // 512KB
    float*          W1T   = (float*)Hh;  // aliases Hh/Hl (dead after gru; w1t runs after)

    hipMemsetAsync(ws, 0, 4096, stream);  // ctr + flags
    detect_k<<<32, 256, 0, stream>>>((const unsigned char*)s_onehot, flags);
    canon_k<<<(BB * TT + 255) / 256, 256, 0, stream>>>(s_onehot, flags, canon);
    h0_k<<<(BB * HH + 255) / 256, 256, 0, stream>>>(encz, Hh, Hl);

    gru_mfma<<<256, 384, 0, stream>>>(dtime, canon, Wih, Whh, bih, bhh,
                                      Hh, Hl, decz, ctr);

    w1t_k<<<(HH * HH + 255) / 256, 256, 0, stream>>>(W1, W1T);
    ff_k<<<BB * TT / 16, 512, 0, stream>>>((const __hip_bfloat16*)(void*)decz,
                                           W1T, b1, W2, b2, decx);

    hipMemsetAsync(d_out, 0, (size_t)out_size * sizeof(float), stream);
    scatter_k<<<2, 256, 0, stream>>>(canon, decx, (float*)d_out);
}

// Round 4
// 4725.597 us; speedup vs baseline: 3.5497x; 1.6677x over previous
//
#include <hip/hip_runtime.h>
#include <hip/hip_bf16.h>

#define BB 256
#define TT 512
#define HH 512

typedef float floatx4 __attribute__((ext_vector_type(4)));
typedef short short8 __attribute__((ext_vector_type(8)));

__device__ __forceinline__ unsigned short f2bf(float f) {
    union { float f; unsigned u; } v; v.f = f;
    unsigned r = v.u + 0x7fffu + ((v.u >> 16) & 1u);
    return (unsigned short)(r >> 16);
}
__device__ __forceinline__ float bf2f(unsigned short h) {
    union { unsigned u; float f; } v; v.u = ((unsigned)h) << 16;
    return v.f;
}
// MFMA A-fragment u32 index for (row b, col j) within a 16x512 tile.
// Layout verified in R2/R3 (absmax = pure bf16 rounding).
__device__ __forceinline__ int frag_idx(int b, int j) {
    int kin = j & 31;
    return (j >> 5) * 512 + ((((kin >> 2) & 3) * 16 + b) << 3) + ((kin >> 4) << 2) + (kin & 3);
}

// ---------------- mask encoding detection ----------------
__global__ void detect_k(const unsigned char* __restrict__ s, int* __restrict__ flags)
{
    int a = 0, b = 0, c = 0;
    for (int i = blockIdx.x * blockDim.x + threadIdx.x; i < BB * TT * 2;
         i += gridDim.x * blockDim.x) {
        unsigned char v = s[i];
        if (v) {
            int m = i & 3;
            if (m == 1) a = 1;
            else if (m >= 2) b = 1;
            if ((i & 7) == 4) c = 1;
        }
    }
    if (a) atomicOr(flags, 1);
    if (b) atomicOr(flags, 2);
    if (c) atomicOr(flags, 4);
}

__global__ void canon_k(const void* __restrict__ s, const int* __restrict__ flags,
                        unsigned char* __restrict__ canon)
{
    int bt = blockIdx.x * blockDim.x + threadIdx.x;
    if (bt >= BB * TT) return;
    int f = *flags;
    int sg, sr;
    if (f & 1) {
        const unsigned char* p = (const unsigned char*)s;
        sg = p[2 * bt] != 0; sr = p[2 * bt + 1] != 0;
    } else if (f & 2) {
        const float* p = (const float*)s;
        sg = p[2 * bt] != 0.0f; sr = p[2 * bt + 1] != 0.0f;
    } else if (f & 4) {
        const int* p = (const int*)s;
        sg = p[2 * bt] != 0; sr = p[2 * bt + 1] != 0;
    } else {
        const long long* p = (const long long*)s;
        sg = p[2 * bt] != 0; sr = p[2 * bt + 1] != 0;
    }
    canon[bt] = (unsigned char)(sg | (sr << 1));
}

// ---------------- h0: encz -> packed hi/lo bf16 in frag order ----------------
__global__ void h0_k(const float* __restrict__ encz, unsigned long long* __restrict__ Hp)
{
    int i = blockIdx.x * blockDim.x + threadIdx.x;   // pair index
    if (i >= BB * HH / 2) return;
    int bg = i >> 8;
    int j  = (i & 255) * 2;
    float f0 = encz[bg * HH + j], f1 = encz[bg * HH + j + 1];
    unsigned short h0b = f2bf(f0), l0b = f2bf(f0 - bf2f(h0b));
    unsigned short h1b = f2bf(f1), l1b = f2bf(f1 - bf2f(h1b));
    unsigned long long p0 = (unsigned)h0b | ((unsigned)l0b << 16);
    unsigned long long p1 = (unsigned)h1b | ((unsigned)l1b << 16);
    int g = bg >> 4, b = bg & 15;
    int F = frag_idx(b, j);
    Hp[(size_t)g * 2 * 4096 + (F >> 1)] = p0 | (p1 << 32);
}

// ---------------- W1 transpose (runs AFTER gru; aliases Hp region) ----------------
__global__ void w1t_k(const float* __restrict__ W1, float* __restrict__ W1T)
{
    int idx = blockIdx.x * blockDim.x + threadIdx.x;
    if (idx >= HH * HH) return;
    int j = idx / HH;
    int k = idx % HH;
    W1T[k * HH + j] = W1[idx];
}

// ---------------- persistent MFMA GRU, fence-free atomic handoff ----------------
// 256 WGs x 384 threads (6 waves). group g = blockIdx&15, wi = blockIdx>>4.
// Group owns batches [16g,16g+16); WG owns cols [32wi,32wi+32); wave = (gate, colhalf).
// h lives in global Hp[group][parity][4096 u64] in EXACT A-frag order, packed
// (bf16hi | bf16lo<<16) per element. All h reads/writes are RELAXED AGENT atomics
// (coherent cross-XCD without L2 wb/inv). Barrier = syncthreads-drain + relaxed
// fetch_add + relaxed poll. Staging is a linear identity copy -> conflict-free LDS.
__global__ __launch_bounds__(384, 2) void gru_mfma(
    const float* __restrict__ dtime, const unsigned char* __restrict__ canon,
    const float* __restrict__ Wih, const float* __restrict__ Whh,
    const float* __restrict__ bih, const float* __restrict__ bhh,
    unsigned long long* __restrict__ Hp,   // [16][2][4096]
    unsigned short* __restrict__ decz,     // [BB][TT][HH] bf16 bits
    int* __restrict__ ctr)
{
    __shared__ unsigned long long hfp64[4096];  // 32KB  A-frags packed
    __shared__ float dtl[16 * 516];             // 33KB  dtime (padded stride)
    __shared__ unsigned char cnl[16 * 520];     // 8.3KB canon (padded stride)
    __shared__ float exch[6 * 256];             // 6KB   C-frag exchange
    __shared__ float pwl[15 * 32];              // 1.9KB pointwise params

    const int g = blockIdx.x & 15, wi = blockIdx.x >> 4;
    const int tid = threadIdx.x, w = tid >> 6, l = tid & 63;
    const int bg0 = g * 16;
    unsigned long long* Hbase = Hp + (size_t)g * 2 * 4096;

    for (int it = tid; it < 16 * 128; it += 384) {
        int b = it >> 7, t4 = it & 127;
        *(float4*)(dtl + b * 516 + t4 * 4) =
            *(const float4*)(dtime + (size_t)(bg0 + b) * TT + t4 * 4);
    }
    for (int it = tid; it < 16 * 128; it += 384) {
        int b = it >> 7, t4 = it & 127;
        *(unsigned*)(cnl + b * 520 + t4 * 4) =
            *(const unsigned*)(canon + (size_t)(bg0 + b) * TT + t4 * 4);
    }
    if (tid < 32) {
        int j = wi * 32 + tid;
        int r1 = HH + j, r2 = 2 * HH + j;
        pwl[0*32+tid] = Wih[j*3];   pwl[1*32+tid] = Wih[j*3+1];  pwl[2*32+tid] = Wih[j*3+2];
        pwl[3*32+tid] = Wih[r1*3];  pwl[4*32+tid] = Wih[r1*3+1]; pwl[5*32+tid] = Wih[r1*3+2];
        pwl[6*32+tid] = Wih[r2*3];  pwl[7*32+tid] = Wih[r2*3+1]; pwl[8*32+tid] = Wih[r2*3+2];
        pwl[9*32+tid]  = bih[j];  pwl[10*32+tid] = bih[r1]; pwl[11*32+tid] = bih[r2];
        pwl[12*32+tid] = bhh[j];  pwl[13*32+tid] = bhh[r1]; pwl[14*32+tid] = bhh[r2];
    }

    // ---- stationary B fragments (W_hh slice, bf16 hi+lo, 128 VGPRs) ----
    const int gate = w >> 1, ch = w & 1;
    const int rB   = gate * HH + wi * 32 + ch * 16 + (l & 15);
    const int kq4  = ((l >> 4) & 3) * 4;
    short8 Bh[16], Bl[16];
#pragma unroll
    for (int kt = 0; kt < 16; ++kt) {
        const float* wp = Whh + (size_t)rB * HH + kt * 32 + kq4;
        float4 f0 = *(const float4*)(wp);
        float4 f1 = *(const float4*)(wp + 16);
        float fs[8] = {f0.x, f0.y, f0.z, f0.w, f1.x, f1.y, f1.z, f1.w};
        short8 bh, bl;
#pragma unroll
        for (int q = 0; q < 8; ++q) {
            unsigned short hb = f2bf(fs[q]);
            bh[q] = (short)hb;
            bl[q] = (short)f2bf(fs[q] - bf2f(hb));
        }
        Bh[kt] = bh; Bl[kt] = bl;
    }

    int* gc = ctr + g * 32;
    __syncthreads();

    for (int t = 0; t < TT; ++t) {
        const unsigned long long* src = Hbase + (size_t)(t & 1) * 4096;
        unsigned long long*       dst = Hbase + (size_t)((t + 1) & 1) * 4096;

        // ---- stage h(t): linear atomic-load -> LDS copy (conflict-free) ----
        for (int it = tid; it < 4096; it += 384)
            hfp64[it] = __hip_atomic_load(src + it, __ATOMIC_RELAXED, __HIP_MEMORY_SCOPE_AGENT);
        __syncthreads();

        // ---- MFMA: unpack hi/lo via v_perm, 3 split-bf16 chains ----
        const unsigned* hp32 = (const unsigned*)hfp64;
        floatx4 ac0 = {0.f,0.f,0.f,0.f}, ac1 = {0.f,0.f,0.f,0.f}, ac2 = {0.f,0.f,0.f,0.f};
#pragma unroll
        for (int kt = 0; kt < 16; ++kt) {
            uint4 wa = *(const uint4*)(hp32 + kt * 512 + l * 8);
            uint4 wb = *(const uint4*)(hp32 + kt * 512 + l * 8 + 4);
            union { unsigned u[4]; short8 s; } uh, ul;
            uh.u[0] = __builtin_amdgcn_perm(wa.y, wa.x, 0x05040100u);
            uh.u[1] = __builtin_amdgcn_perm(wa.w, wa.z, 0x05040100u);
            uh.u[2] = __builtin_amdgcn_perm(wb.y, wb.x, 0x05040100u);
            uh.u[3] = __builtin_amdgcn_perm(wb.w, wb.z, 0x05040100u);
            ul.u[0] = __builtin_amdgcn_perm(wa.y, wa.x, 0x07060302u);
            ul.u[1] = __builtin_amdgcn_perm(wa.w, wa.z, 0x07060302u);
            ul.u[2] = __builtin_amdgcn_perm(wb.y, wb.x, 0x07060302u);
            ul.u[3] = __builtin_amdgcn_perm(wb.w, wb.z, 0x07060302u);
            ac0 = __builtin_amdgcn_mfma_f32_16x16x32_bf16(uh.s, Bh[kt], ac0, 0, 0, 0);
            ac1 = __builtin_amdgcn_mfma_f32_16x16x32_bf16(uh.s, Bl[kt], ac1, 0, 0, 0);
            ac2 = __builtin_amdgcn_mfma_f32_16x16x32_bf16(ul.s, Bh[kt], ac2, 0, 0, 0);
        }
        floatx4 acc = ac0 + ac1 + ac2;
        *(floatx4*)(exch + w * 256 + l * 4) = acc;
        __syncthreads();

        // ---- pointwise GRU update (threads < 256, 2 cols each) ----
        if (tid < 256) {
            const int b = tid >> 4;
            const int bgl = bg0 + b;
            const float dt = dtl[b * 516 + t];
            const unsigned char cn = cnl[b * 520 + t];
            const float sg = (cn & 1) ? 1.f : 0.f, sr = (cn & 2) ? 1.f : 0.f;
            unsigned pack[2]; unsigned short hib[2];
#pragma unroll
            for (int p = 0; p < 2; ++p) {
                int jl = (tid * 2 + p) & 31;
                int j  = wi * 32 + jl;
                int lane16 = (jl & 15) + 16 * (b >> 2);
                int roff = b & 3;
                float a0 = exch[(jl >> 4) * 256 + lane16 * 4 + roff];
                float a1 = exch[(2 + (jl >> 4)) * 256 + lane16 * 4 + roff];
                float a2 = exch[(4 + (jl >> 4)) * 256 + lane16 * 4 + roff];
                unsigned hv = ((const unsigned*)hfp64)[frag_idx(b, j)];
                float hp = bf2f((unsigned short)(hv & 0xffffu)) +
                           bf2f((unsigned short)(hv >> 16));
                float xr = pwl[0*32+jl]*dt + pwl[1*32+jl]*sg + pwl[2*32+jl]*sr + pwl[9*32+jl];
                float xz = pwl[3*32+jl]*dt + pwl[4*32+jl]*sg + pwl[5*32+jl]*sr + pwl[10*32+jl];
                float xn = pwl[6*32+jl]*dt + pwl[7*32+jl]*sg + pwl[8*32+jl]*sr + pwl[11*32+jl];
                float rr = 1.f / (1.f + __expf(-(xr + a0 + pwl[12*32+jl])));
                float zz = 1.f / (1.f + __expf(-(xz + a1 + pwl[13*32+jl])));
                float tx = xn + rr * (a2 + pwl[14*32+jl]);
                float ex2 = __expf(2.f * fminf(fmaxf(tx, -20.f), 20.f));
                float nn = 1.f - 2.f / (ex2 + 1.f);
                float hnew = (1.f - zz) * nn + zz * hp;
                float ho = cn ? hnew : hp;
                unsigned short hb = f2bf(ho);
                unsigned short lb = f2bf(ho - bf2f(hb));
                pack[p] = (unsigned)hb | ((unsigned)lb << 16);
                hib[p] = hb;
            }
            int j0 = wi * 32 + ((tid * 2) & 31);
            int F0 = frag_idx(b, j0);
            unsigned long long hv64 =
                (unsigned long long)pack[0] | ((unsigned long long)pack[1] << 32);
            __hip_atomic_store(dst + (F0 >> 1), hv64,
                               __ATOMIC_RELAXED, __HIP_MEMORY_SCOPE_AGENT);
            ((unsigned*)decz)[(((size_t)bgl * TT + t) * HH + j0) >> 1] =
                (unsigned)hib[0] | ((unsigned)hib[1] << 16);
        }

        // ---- fence-free group barrier ----
        if (t != TT - 1) {
            __syncthreads();   // compiler drains vmcnt(0) before s_barrier -> stores complete
            if (tid == 0) {
                __hip_atomic_fetch_add(gc, 1, __ATOMIC_RELAXED, __HIP_MEMORY_SCOPE_AGENT);
                int tgt = (t + 1) * 16;
                while (__hip_atomic_load(gc, __ATOMIC_RELAXED, __HIP_MEMORY_SCOPE_AGENT) < tgt)
                    __builtin_amdgcn_s_sleep(1);
            }
            __syncthreads();
        }
    }
}

// ---------------- FF head ----------------
__global__ __launch_bounds__(512) void ff_k(
    const __hip_bfloat16* __restrict__ decz, const float* __restrict__ W1T,
    const float* __restrict__ b1, const float* __restrict__ W2,
    const float* __restrict__ b2, float* __restrict__ decx)
{
    __shared__ float xl[16 * 512];
    __shared__ float red[8];

    const int row0 = blockIdx.x * 16;
    for (int idx = threadIdx.x; idx < 16 * 512; idx += 512) {
        int rr = idx >> 9, k = idx & 511;
        xl[rr * 512 + k] = __bfloat162float(decz[(size_t)(row0 + rr) * HH + k]);
    }
    __syncthreads();

    const int j = threadIdx.x;
    float acc[16];
#pragma unroll
    for (int rr = 0; rr < 16; rr++) acc[rr] = 0.f;

    for (int k = 0; k < 512; k++) {
        float wv = W1T[k * 512 + j];
#pragma unroll
        for (int rr = 0; rr < 16; rr++) acc[rr] += xl[rr * 512 + k] * wv;
    }

    const float w2j = W2[j];
    const float b1j = b1[j];
    for (int rr = 0; rr < 16; rr++) {
        float v = w2j * fmaxf(acc[rr] + b1j, 0.f);
#pragma unroll
        for (int o = 32; o > 0; o >>= 1) v += __shfl_down(v, o, 64);
        if ((threadIdx.x & 63) == 0) red[threadIdx.x >> 6] = v;
        __syncthreads();
        if (threadIdx.x == 0) {
            float s = 0.f;
#pragma unroll
            for (int ww = 0; ww < 8; ww++) s += red[ww];
            decx[row0 + rr] = s + b2[0];
        }
        __syncthreads();
    }
}

// ---------------- serial -> parallel scatter ----------------
__global__ void scatter_k(const unsigned char* __restrict__ canon,
                          const float* __restrict__ decx, float* __restrict__ out)
{
    int id = blockIdx.x * blockDim.x + threadIdx.x;
    if (id >= 2 * BB) return;
    int kb = id >> 8, b = id & 255;
    int cnt = 0;
    for (int t = 0; t < TT; t++) {
        unsigned char c = canon[b * TT + t];
        if ((c >> kb) & 1) {
            out[((size_t)kb * BB + b) * TT + cnt] = decx[b * TT + t];
            cnt++;
        }
    }
}

extern "C" void kernel_launch(void* const* d_in, const int* in_sizes, int n_in,
                              void* d_out, int out_size, void* d_ws, size_t ws_size,
                              hipStream_t stream)
{
    const float* dtime    = (const float*)d_in[0];
    const void*  s_onehot = d_in[1];
    // d_in[2] (onehot/valid) never read: valid == s_g | s_r by construction.
    const float* encz = (const float*)d_in[3];
    const float* Wih  = (const float*)d_in[4];
    const float* Whh  = (const float*)d_in[5];
    const float* bih  = (const float*)d_in[6];
    const float* bhh  = (const float*)d_in[7];
    const float* W1   = (const float*)d_in[8];
    const float* b1   = (const float*)d_in[9];
    const float* W2   = (const float*)d_in[10];
    const float* b2   = (const float*)d_in[11];

    char* ws = (char*)d_ws;
    int*                ctr   = (int*)ws;                        // 2KB
    int*                flags = (int*)(ws + 2048);               // 2KB
    unsigned char*      canon = (unsigned char*)(ws + 4096);     // 128KB
    unsigned long long* Hp    = (unsigned long long*)(ws + 4096 + BB * TT);      // 1MB
    unsigned short*     decz  = (unsigned short*)((char*)Hp + 16 * 2 * 4096 * 8); // 128MB
    float*              decx  = (float*)(decz + (size_t)BB * TT * HH);            // 512KB
    float*              W1T   = (float*)Hp;   // aliases Hp (dead after gru)

    hipMemsetAsync(ws, 0, 4096, stream);   // ctr + flags
    detect_k<<<32, 256, 0, stream>>>((const unsigned char*)s_onehot, flags);
    canon_k<<<(BB * TT + 255) / 256, 256, 0, stream>>>(s_onehot, flags, canon);
    h0_k<<<(BB * HH / 2 + 255) / 256, 256, 0, stream>>>(encz, Hp);

    gru_mfma<<<256, 384, 0, stream>>>(dtime, canon, Wih, Whh, bih, bhh,
                                      Hp, decz, ctr);

    w1t_k<<<(HH * HH + 255) / 256, 256, 0, stream>>>(W1, W1T);
    ff_k<<<BB * TT / 16, 512, 0, stream>>>((const __hip_bfloat16*)(void*)decz,
                                           W1T, b1, W2, b2, decx);

    hipMemsetAsync(d_out, 0, (size_t)out_size * sizeof(float), stream);
    scatter_k<<<2, 256, 0, stream>>>(canon, decx, (float*)d_out);
}